// Round 1
// baseline (1963.388 us; speedup 1.0000x reference)
//
#include <hip/hip_runtime.h>
#include <hip/hip_bf16.h>

// LuongAttention on MI355X.
//   P = Q @ W^T                      (keys GEMM eliminated via associativity)
//   S = P @ V^T   (raw scores -> alignment region of d_out)
//   A = softmax(S) in-place
//   context = A @ V                  (V pre-transposed to bf16 in ws)
// W_bias is softmax-invariant (adds a per-row constant to scores) -> dropped.
// P/S GEMMs use 3-term bf16-split MFMA for near-fp32 scores (sharp softmax!).

#define B_  16
#define TQ_ 2048
#define TV_ 2048
#define D_  1024
#define U_  1024

typedef __attribute__((ext_vector_type(8))) short bf16x8;  // 8 bf16 = 4 VGPRs
typedef __attribute__((ext_vector_type(4))) float f32x4;

__device__ __forceinline__ short f2bf(float x) {
    union { float f; unsigned u; } v; v.f = x;
    unsigned r = v.u + 0x7fffu + ((v.u >> 16) & 1u);   // RNE
    return (short)(r >> 16);
}
__device__ __forceinline__ float bf2f(short h) {
    union { unsigned u; float f; } v;
    v.u = ((unsigned)(unsigned short)h) << 16;
    return v.f;
}

#define BK  32
#define LDK 40   // 80B row stride -> ~2-way LDS bank aliasing (free, m136)

// C[M,N] += A[M,K] . B[N,K]^T, fp32 in/out, 3-term bf16 split MFMA.
// 128x128 C-tile per 256-thread block; blockIdx.z = batch (strides sA/sB/sC).
__global__ __launch_bounds__(256, 2) void gemm_nt_split(
    const float* __restrict__ A, const float* __restrict__ Bm, float* __restrict__ C,
    int lda, int ldb, int ldc, int K, size_t sA, size_t sB, size_t sC)
{
    __shared__ short sAhi[128 * LDK], sAlo[128 * LDK], sBhi[128 * LDK], sBlo[128 * LDK];
    const int tid = threadIdx.x;
    const int lane = tid & 63, wave = tid >> 6;
    const int wm = (wave >> 1) << 6, wn = (wave & 1) << 6;   // 2x2 waves of 64x64
    const int l15 = lane & 15, l4 = lane >> 4;
    const size_t row0 = (size_t)blockIdx.y << 7, col0 = (size_t)blockIdx.x << 7;
    const float* Ab = A + (size_t)blockIdx.z * sA + row0 * (size_t)lda;
    const float* Bb = Bm + (size_t)blockIdx.z * sB + col0 * (size_t)ldb;

    f32x4 acc[4][4];
    for (int i = 0; i < 4; ++i)
        for (int j = 0; j < 4; ++j)
            acc[i][j] = (f32x4){0.f, 0.f, 0.f, 0.f};

    for (int kt = 0; kt < K; kt += BK) {
        __syncthreads();
        // stage 128x32 fp32 tiles of A and B, splitting to hi/lo bf16 in LDS
        for (int r = 0; r < 4; ++r) {
            const int flat = (r << 8) + tid;            // 0..1023
            const int row = flat >> 3, c = (flat & 7) << 2;
            const float4 va = *(const float4*)(Ab + (size_t)row * lda + kt + c);
            const float4 vb = *(const float4*)(Bb + (size_t)row * ldb + kt + c);
            short4 h, l;
            h.x = f2bf(va.x); l.x = f2bf(va.x - bf2f(h.x));
            h.y = f2bf(va.y); l.y = f2bf(va.y - bf2f(h.y));
            h.z = f2bf(va.z); l.z = f2bf(va.z - bf2f(h.z));
            h.w = f2bf(va.w); l.w = f2bf(va.w - bf2f(h.w));
            *(short4*)&sAhi[row * LDK + c] = h;
            *(short4*)&sAlo[row * LDK + c] = l;
            h.x = f2bf(vb.x); l.x = f2bf(vb.x - bf2f(h.x));
            h.y = f2bf(vb.y); l.y = f2bf(vb.y - bf2f(h.y));
            h.z = f2bf(vb.z); l.z = f2bf(vb.z - bf2f(h.z));
            h.w = f2bf(vb.w); l.w = f2bf(vb.w - bf2f(h.w));
            *(short4*)&sBhi[row * LDK + c] = h;
            *(short4*)&sBlo[row * LDK + c] = l;
        }
        __syncthreads();
        // fragments: A[m=lane&15][k=(lane>>4)*8+j], same pattern for B (NT)
        const int ko = l4 << 3;
        bf16x8 ah[4], al[4], bh[4], bl[4];
        for (int i = 0; i < 4; ++i) {
            ah[i] = *(const bf16x8*)&sAhi[(wm + (i << 4) + l15) * LDK + ko];
            al[i] = *(const bf16x8*)&sAlo[(wm + (i << 4) + l15) * LDK + ko];
            bh[i] = *(const bf16x8*)&sBhi[(wn + (i << 4) + l15) * LDK + ko];
            bl[i] = *(const bf16x8*)&sBlo[(wn + (i << 4) + l15) * LDK + ko];
        }
        for (int i = 0; i < 4; ++i)
            for (int j = 0; j < 4; ++j) {
                acc[i][j] = __builtin_amdgcn_mfma_f32_16x16x32_bf16(ah[i], bh[j], acc[i][j], 0, 0, 0);
                acc[i][j] = __builtin_amdgcn_mfma_f32_16x16x32_bf16(ah[i], bl[j], acc[i][j], 0, 0, 0);
                acc[i][j] = __builtin_amdgcn_mfma_f32_16x16x32_bf16(al[i], bh[j], acc[i][j], 0, 0, 0);
            }
    }

    // C/D layout (16x16x32): col = lane&15, row = (lane>>4)*4 + reg  [m89/m91]
    float* Cb = C + (size_t)blockIdx.z * sC;
    for (int i = 0; i < 4; ++i)
        for (int j = 0; j < 4; ++j)
            for (int r = 0; r < 4; ++r)
                Cb[(row0 + wm + (i << 4) + (l4 << 2) + r) * (size_t)ldc
                   + col0 + wn + (j << 4) + l15] = acc[i][j][r];
}

// C[M,N] = A[M,K] . Bt[N,K]^T, A fp32 (converted to bf16 hi-only), Bt already bf16.
__global__ __launch_bounds__(256, 2) void gemm_nt_af32_bbf16(
    const float* __restrict__ A, const short* __restrict__ Bt, float* __restrict__ C,
    int lda, int ldb, int ldc, int K, size_t sA, size_t sB, size_t sC)
{
    __shared__ short sA16[128 * LDK], sB16[128 * LDK];
    const int tid = threadIdx.x;
    const int lane = tid & 63, wave = tid >> 6;
    const int wm = (wave >> 1) << 6, wn = (wave & 1) << 6;
    const int l15 = lane & 15, l4 = lane >> 4;
    const size_t row0 = (size_t)blockIdx.y << 7, col0 = (size_t)blockIdx.x << 7;
    const float* Ab = A + (size_t)blockIdx.z * sA + row0 * (size_t)lda;
    const short* Bb = Bt + (size_t)blockIdx.z * sB + col0 * (size_t)ldb;

    f32x4 acc[4][4];
    for (int i = 0; i < 4; ++i)
        for (int j = 0; j < 4; ++j)
            acc[i][j] = (f32x4){0.f, 0.f, 0.f, 0.f};

    for (int kt = 0; kt < K; kt += BK) {
        __syncthreads();
        for (int r = 0; r < 4; ++r) {
            const int flat = (r << 8) + tid;            // 0..1023
            const int row = flat >> 3, c = (flat & 7) << 2;
            const float4 va = *(const float4*)(Ab + (size_t)row * lda + kt + c);
            short4 h;
            h.x = f2bf(va.x); h.y = f2bf(va.y); h.z = f2bf(va.z); h.w = f2bf(va.w);
            *(short4*)&sA16[row * LDK + c] = h;
        }
        for (int r = 0; r < 2; ++r) {
            const int flat = (r << 8) + tid;            // 0..511
            const int row = flat >> 2, c = (flat & 3) << 3;   // 8 shorts each
            *(bf16x8*)&sB16[row * LDK + c] =
                *(const bf16x8*)(Bb + (size_t)row * ldb + kt + c);
        }
        __syncthreads();
        const int ko = l4 << 3;
        bf16x8 ah[4], bh[4];
        for (int i = 0; i < 4; ++i) {
            ah[i] = *(const bf16x8*)&sA16[(wm + (i << 4) + l15) * LDK + ko];
            bh[i] = *(const bf16x8*)&sB16[(wn + (i << 4) + l15) * LDK + ko];
        }
        for (int i = 0; i < 4; ++i)
            for (int j = 0; j < 4; ++j)
                acc[i][j] = __builtin_amdgcn_mfma_f32_16x16x32_bf16(ah[i], bh[j], acc[i][j], 0, 0, 0);
    }

    float* Cb = C + (size_t)blockIdx.z * sC;
    for (int i = 0; i < 4; ++i)
        for (int j = 0; j < 4; ++j)
            for (int r = 0; r < 4; ++r)
                Cb[(row0 + wm + (i << 4) + (l4 << 2) + r) * (size_t)ldc
                   + col0 + wn + (j << 4) + l15] = acc[i][j][r];
}

// values[b][v][d] fp32 -> Vt[b][d][v] bf16
__global__ __launch_bounds__(256) void transpose_bf16(
    const float* __restrict__ V, short* __restrict__ Vt)
{
    __shared__ float tile[32][33];
    const int b = blockIdx.z;
    const int d0 = blockIdx.x << 5, v0 = blockIdx.y << 5;
    const float* Vb = V + (size_t)b * TV_ * D_;
    short* Vtb = Vt + (size_t)b * D_ * TV_;
    const int tx = threadIdx.x, ty = threadIdx.y;   // 32 x 8
    for (int k = 0; k < 4; ++k)
        tile[ty + (k << 3)][tx] = Vb[(size_t)(v0 + ty + (k << 3)) * D_ + d0 + tx];
    __syncthreads();
    for (int k = 0; k < 4; ++k)
        Vtb[(size_t)(d0 + ty + (k << 3)) * TV_ + v0 + tx] = f2bf(tile[tx][ty + (k << 3)]);
}

// in-place softmax over rows of length 2048; one 256-thread block per row
__global__ __launch_bounds__(256) void softmax_rows(float* __restrict__ S)
{
    float* p = S + (size_t)blockIdx.x * TV_;
    const int t = threadIdx.x;
    const int lane = t & 63, wave = t >> 6;
    float4 a = *(const float4*)(p + (t << 2));
    float4 b = *(const float4*)(p + 1024 + (t << 2));
    float m = fmaxf(fmaxf(fmaxf(a.x, a.y), fmaxf(a.z, a.w)),
                    fmaxf(fmaxf(b.x, b.y), fmaxf(b.z, b.w)));
    for (int off = 32; off; off >>= 1) m = fmaxf(m, __shfl_xor(m, off, 64));
    __shared__ float redm[4], reds[4];
    if (lane == 0) redm[wave] = m;
    __syncthreads();
    m = fmaxf(fmaxf(redm[0], redm[1]), fmaxf(redm[2], redm[3]));
    a.x = __expf(a.x - m); a.y = __expf(a.y - m);
    a.z = __expf(a.z - m); a.w = __expf(a.w - m);
    b.x = __expf(b.x - m); b.y = __expf(b.y - m);
    b.z = __expf(b.z - m); b.w = __expf(b.w - m);
    float s = a.x + a.y + a.z + a.w + b.x + b.y + b.z + b.w;
    for (int off = 32; off; off >>= 1) s += __shfl_xor(s, off, 64);
    if (lane == 0) reds[wave] = s;
    __syncthreads();
    s = reds[0] + reds[1] + reds[2] + reds[3];
    const float inv = 1.0f / s;
    a.x *= inv; a.y *= inv; a.z *= inv; a.w *= inv;
    b.x *= inv; b.y *= inv; b.z *= inv; b.w *= inv;
    *(float4*)(p + (t << 2)) = a;
    *(float4*)(p + 1024 + (t << 2)) = b;
}

extern "C" void kernel_launch(void* const* d_in, const int* in_sizes, int n_in,
                              void* d_out, int out_size, void* d_ws, size_t ws_size,
                              hipStream_t stream)
{
    const float* query  = (const float*)d_in[0];   // [16,2048,1024]
    const float* values = (const float*)d_in[1];   // [16,2048,1024]
    const float* Wk     = (const float*)d_in[2];   // [1024,1024]  (W_bias d_in[3] unused: softmax-invariant)

    float* context = (float*)d_out;                          // [16,2048,1024]
    float* align   = (float*)d_out + (size_t)B_ * TQ_ * D_;  // [16,2048,2048]
    float* P       = context;       // reuse: same size, dead before context written
    short* Vt      = (short*)d_ws;  // [16,1024,2048] bf16, 64 MiB

    // 1. Vt = bf16(values^T) per batch
    transpose_bf16<<<dim3(D_ / 32, TV_ / 32, B_), dim3(32, 8), 0, stream>>>(values, Vt);

    // 2. P = Q @ W^T   (M=32768, N=1024, K=1024), split precision
    gemm_nt_split<<<dim3(D_ / 128, (B_ * TQ_) / 128, 1), 256, 0, stream>>>(
        query, Wk, P, U_, U_, D_, U_, 0, 0, 0);

    // 3. S = P @ V^T per batch -> raw scores into alignment region
    gemm_nt_split<<<dim3(TV_ / 128, TQ_ / 128, B_), 256, 0, stream>>>(
        P, values, align, D_, D_, TV_, D_,
        (size_t)TQ_ * D_, (size_t)TV_ * D_, (size_t)TQ_ * TV_);

    // 4. alignment = softmax(S) in place
    softmax_rows<<<B_ * TQ_, 256, 0, stream>>>(align);

    // 5. context = alignment @ V per batch (A fp32->bf16, B = Vt bf16)
    gemm_nt_af32_bbf16<<<dim3(D_ / 128, TQ_ / 128, B_), 256, 0, stream>>>(
        align, Vt, context, TV_, TV_, D_, TV_,
        (size_t)TQ_ * TV_, (size_t)D_ * TV_, (size_t)TQ_ * D_);
}

// Round 2
// 1570.424 us; speedup vs baseline: 1.2502x; 1.2502x over previous
//
#include <hip/hip_runtime.h>
#include <hip/hip_bf16.h>

// LuongAttention on MI355X — round 2.
//   P = Q @ W^T (split-bf16 planes), S = P @ V^T (split planes), softmax,
//   context = A @ V (bf16).
// All heavy GEMMs use the m97 structure: global_load_lds dwordx4 staging into
// unpadded 64B-row LDS tiles, ds_read_b128 fragments, 16x16x32 bf16 MFMA.
// Precision: 3-term bf16 split (hi*hi + hi*lo + lo*hi) for P and S.
// W_bias is softmax-invariant -> dropped.

#define B_  16
#define TQ_ 2048
#define TV_ 2048
#define D_  1024
#define U_  1024

typedef __attribute__((ext_vector_type(8))) short bf16x8;  // 8 bf16 = 4 VGPRs
typedef __attribute__((ext_vector_type(4))) float f32x4;

__device__ __forceinline__ short f2bf(float x) {
    union { float f; unsigned u; } v; v.f = x;
    unsigned r = v.u + 0x7fffu + ((v.u >> 16) & 1u);   // RNE
    return (short)(r >> 16);
}
__device__ __forceinline__ float bf2f(short h) {
    union { unsigned u; float f; } v;
    v.u = ((unsigned)(unsigned short)h) << 16;
    return v.f;
}

// async global->LDS, 16B per lane; lds base must be wave-uniform (m104/m108)
__device__ __forceinline__ void gld16(const short* g, short* l) {
    __builtin_amdgcn_global_load_lds(
        (const __attribute__((address_space(1))) void*)g,
        (__attribute__((address_space(3))) void*)l, 16, 0, 0);
}

// ---------------------------------------------------------------------------
// C = Ahi/lo . (Bhi/lo)^T  with 3-term split MFMA. 128x128 tile, BK=32.
// SPLIT_OUT=1: write C as (Chi,Clo) bf16 planes; else fp32 C.
// ---------------------------------------------------------------------------
template<int SPLIT_OUT>
__global__ __launch_bounds__(256, 2) void gemm_nt_planes(
    const short* __restrict__ Ahi, const short* __restrict__ Alo,
    const short* __restrict__ Bhi, const short* __restrict__ Blo,
    float* __restrict__ C, short* __restrict__ Chi, short* __restrict__ Clo,
    int lda, int ldb, int ldc, int K, size_t sA, size_t sB, size_t sC)
{
    __shared__ short sAhi[128 * 32], sAlo[128 * 32], sBhi[128 * 32], sBlo[128 * 32];
    const int tid = threadIdx.x;
    const int lane = tid & 63, wave = tid >> 6;
    const int wm = (wave >> 1) << 6, wn = (wave & 1) << 6;   // 2x2 waves of 64x64
    const int l15 = lane & 15, l4 = lane >> 4;
    const int lr = lane >> 2, lc = (lane & 3) << 3;          // staging: 16 rows/issue
    const size_t row0 = (size_t)blockIdx.y << 7, col0 = (size_t)blockIdx.x << 7;
    const short* Abh = Ahi + (size_t)blockIdx.z * sA + row0 * (size_t)lda;
    const short* Abl = Alo + (size_t)blockIdx.z * sA + row0 * (size_t)lda;
    const short* Bbh = Bhi + (size_t)blockIdx.z * sB + col0 * (size_t)ldb;
    const short* Bbl = Blo + (size_t)blockIdx.z * sB + col0 * (size_t)ldb;

    f32x4 acc[4][4];
    for (int i = 0; i < 4; ++i)
        for (int j = 0; j < 4; ++j)
            acc[i][j] = (f32x4){0.f, 0.f, 0.f, 0.f};

    for (int kt = 0; kt < K; kt += 32) {
        __syncthreads();
        for (int t = 0; t < 2; ++t) {
            const int rbase = (wave << 5) + (t << 4);        // wave-uniform
            const size_t ga = (size_t)(rbase + lr) * lda + kt + lc;
            const size_t gb = (size_t)(rbase + lr) * ldb + kt + lc;
            const int lb = rbase << 5;                       // *32 shorts
            gld16(Abh + ga, &sAhi[lb]);
            gld16(Abl + ga, &sAlo[lb]);
            gld16(Bbh + gb, &sBhi[lb]);
            gld16(Bbl + gb, &sBlo[lb]);
        }
        __syncthreads();
        const int ko = l4 << 3;
        bf16x8 ah[4], al[4], bh[4], bl[4];
        for (int i = 0; i < 4; ++i) {
            ah[i] = *(const bf16x8*)&sAhi[((wm + (i << 4) + l15) << 5) + ko];
            al[i] = *(const bf16x8*)&sAlo[((wm + (i << 4) + l15) << 5) + ko];
            bh[i] = *(const bf16x8*)&sBhi[((wn + (i << 4) + l15) << 5) + ko];
            bl[i] = *(const bf16x8*)&sBlo[((wn + (i << 4) + l15) << 5) + ko];
        }
        for (int i = 0; i < 4; ++i)
            for (int j = 0; j < 4; ++j) {
                acc[i][j] = __builtin_amdgcn_mfma_f32_16x16x32_bf16(ah[i], bh[j], acc[i][j], 0, 0, 0);
                acc[i][j] = __builtin_amdgcn_mfma_f32_16x16x32_bf16(ah[i], bl[j], acc[i][j], 0, 0, 0);
                acc[i][j] = __builtin_amdgcn_mfma_f32_16x16x32_bf16(al[i], bh[j], acc[i][j], 0, 0, 0);
            }
    }

    // C/D layout (16x16x32): col = lane&15, row = (lane>>4)*4 + reg  [m89/m91]
    if (SPLIT_OUT) {
        for (int i = 0; i < 4; ++i)
            for (int j = 0; j < 4; ++j)
                for (int r = 0; r < 4; ++r) {
                    const float x = acc[i][j][r];
                    const short h = f2bf(x);
                    const short l = f2bf(x - bf2f(h));
                    const size_t idx = (row0 + wm + (i << 4) + (l4 << 2) + r) * (size_t)ldc
                                       + col0 + wn + (j << 4) + l15;
                    Chi[idx] = h;
                    Clo[idx] = l;
                }
    } else {
        float* Cb = C + (size_t)blockIdx.z * sC;
        for (int i = 0; i < 4; ++i)
            for (int j = 0; j < 4; ++j)
                for (int r = 0; r < 4; ++r)
                    Cb[(row0 + wm + (i << 4) + (l4 << 2) + r) * (size_t)ldc
                       + col0 + wn + (j << 4) + l15] = acc[i][j][r];
    }
}

// ---------------------------------------------------------------------------
// context = A[M,K] . Bt[N,K]^T; A fp32 (fused bf16 convert), Bt bf16 (lds-direct)
// ---------------------------------------------------------------------------
__global__ __launch_bounds__(256, 2) void gemm_ctx(
    const float* __restrict__ A, const short* __restrict__ Bt, float* __restrict__ C,
    int lda, int ldb, int ldc, int K, size_t sA, size_t sB, size_t sC)
{
    __shared__ short sA16[128 * 32], sB16[128 * 32];
    const int tid = threadIdx.x;
    const int lane = tid & 63, wave = tid >> 6;
    const int wm = (wave >> 1) << 6, wn = (wave & 1) << 6;
    const int l15 = lane & 15, l4 = lane >> 4;
    const int lr = lane >> 2, lc = (lane & 3) << 3;
    const size_t row0 = (size_t)blockIdx.y << 7, col0 = (size_t)blockIdx.x << 7;
    const float* Ab = A + (size_t)blockIdx.z * sA + row0 * (size_t)lda;
    const short* Bb = Bt + (size_t)blockIdx.z * sB + col0 * (size_t)ldb;

    f32x4 acc[4][4];
    for (int i = 0; i < 4; ++i)
        for (int j = 0; j < 4; ++j)
            acc[i][j] = (f32x4){0.f, 0.f, 0.f, 0.f};

    for (int kt = 0; kt < K; kt += 32) {
        __syncthreads();
        for (int r = 0; r < 4; ++r) {
            const int flat = (r << 8) + tid;            // 0..1023
            const int row = flat >> 3, c = (flat & 7) << 2;
            const float4 va = *(const float4*)(Ab + (size_t)row * lda + kt + c);
            short4 h;
            h.x = f2bf(va.x); h.y = f2bf(va.y); h.z = f2bf(va.z); h.w = f2bf(va.w);
            *(short4*)&sA16[(row << 5) + c] = h;
        }
        for (int t = 0; t < 2; ++t) {
            const int rbase = (wave << 5) + (t << 4);
            gld16(Bb + (size_t)(rbase + lr) * ldb + kt + lc, &sB16[rbase << 5]);
        }
        __syncthreads();
        const int ko = l4 << 3;
        bf16x8 ah[4], bh[4];
        for (int i = 0; i < 4; ++i) {
            ah[i] = *(const bf16x8*)&sA16[((wm + (i << 4) + l15) << 5) + ko];
            bh[i] = *(const bf16x8*)&sB16[((wn + (i << 4) + l15) << 5) + ko];
        }
        for (int i = 0; i < 4; ++i)
            for (int j = 0; j < 4; ++j)
                acc[i][j] = __builtin_amdgcn_mfma_f32_16x16x32_bf16(ah[i], bh[j], acc[i][j], 0, 0, 0);
    }

    float* Cb = C + (size_t)blockIdx.z * sC;
    for (int i = 0; i < 4; ++i)
        for (int j = 0; j < 4; ++j)
            for (int r = 0; r < 4; ++r)
                Cb[(row0 + wm + (i << 4) + (l4 << 2) + r) * (size_t)ldc
                   + col0 + wn + (j << 4) + l15] = acc[i][j][r];
}

// elementwise fp32 -> (hi,lo) bf16 planes, 4 elems/thread
__global__ __launch_bounds__(256) void split_f32(
    const float* __restrict__ X, short* __restrict__ hi, short* __restrict__ lo)
{
    const size_t i = ((size_t)blockIdx.x * 256 + threadIdx.x) << 2;
    const float4 v = *(const float4*)(X + i);
    short4 h, l;
    h.x = f2bf(v.x); l.x = f2bf(v.x - bf2f(h.x));
    h.y = f2bf(v.y); l.y = f2bf(v.y - bf2f(h.y));
    h.z = f2bf(v.z); l.z = f2bf(v.z - bf2f(h.z));
    h.w = f2bf(v.w); l.w = f2bf(v.w - bf2f(h.w));
    *(short4*)(hi + i) = h;
    *(short4*)(lo + i) = l;
}

// values[b][v][d] -> Vhi/Vlo (same layout) + Vt[b][d][v] bf16 (hi only)
__global__ __launch_bounds__(256) void split_values(
    const float* __restrict__ V, short* __restrict__ Vhi,
    short* __restrict__ Vlo, short* __restrict__ Vt)
{
    __shared__ float tile[32][33];
    const int b = blockIdx.z;
    const int d0 = blockIdx.x << 5, v0 = blockIdx.y << 5;
    const float* Vb = V + (size_t)b * TV_ * D_;
    const size_t pb = (size_t)b * TV_ * D_;
    short* Vtb = Vt + (size_t)b * D_ * TV_;
    const int tx = threadIdx.x, ty = threadIdx.y;   // 32 x 8
    for (int k = 0; k < 4; ++k) {
        const int v = v0 + ty + (k << 3);
        const float x = Vb[(size_t)v * D_ + d0 + tx];
        tile[ty + (k << 3)][tx] = x;
        const short h = f2bf(x);
        Vhi[pb + (size_t)v * D_ + d0 + tx] = h;
        Vlo[pb + (size_t)v * D_ + d0 + tx] = f2bf(x - bf2f(h));
    }
    __syncthreads();
    for (int k = 0; k < 4; ++k)
        Vtb[(size_t)(d0 + ty + (k << 3)) * TV_ + v0 + tx] = f2bf(tile[tx][ty + (k << 3)]);
}

// in-place softmax over rows of length 2048; one 256-thread block per row
__global__ __launch_bounds__(256) void softmax_rows(float* __restrict__ S)
{
    float* p = S + (size_t)blockIdx.x * TV_;
    const int t = threadIdx.x;
    const int lane = t & 63, wave = t >> 6;
    float4 a = *(const float4*)(p + (t << 2));
    float4 b = *(const float4*)(p + 1024 + (t << 2));
    float m = fmaxf(fmaxf(fmaxf(a.x, a.y), fmaxf(a.z, a.w)),
                    fmaxf(fmaxf(b.x, b.y), fmaxf(b.z, b.w)));
    for (int off = 32; off; off >>= 1) m = fmaxf(m, __shfl_xor(m, off, 64));
    __shared__ float redm[4], reds[4];
    if (lane == 0) redm[wave] = m;
    __syncthreads();
    m = fmaxf(fmaxf(redm[0], redm[1]), fmaxf(redm[2], redm[3]));
    a.x = __expf(a.x - m); a.y = __expf(a.y - m);
    a.z = __expf(a.z - m); a.w = __expf(a.w - m);
    b.x = __expf(b.x - m); b.y = __expf(b.y - m);
    b.z = __expf(b.z - m); b.w = __expf(b.w - m);
    float s = a.x + a.y + a.z + a.w + b.x + b.y + b.z + b.w;
    for (int off = 32; off; off >>= 1) s += __shfl_xor(s, off, 64);
    if (lane == 0) reds[wave] = s;
    __syncthreads();
    s = reds[0] + reds[1] + reds[2] + reds[3];
    const float inv = 1.0f / s;
    a.x *= inv; a.y *= inv; a.z *= inv; a.w *= inv;
    b.x *= inv; b.y *= inv; b.z *= inv; b.w *= inv;
    *(float4*)(p + (t << 2)) = a;
    *(float4*)(p + 1024 + (t << 2)) = b;
}

extern "C" void kernel_launch(void* const* d_in, const int* in_sizes, int n_in,
                              void* d_out, int out_size, void* d_ws, size_t ws_size,
                              hipStream_t stream)
{
    const float* query  = (const float*)d_in[0];   // [16,2048,1024]
    const float* values = (const float*)d_in[1];   // [16,2048,1024]
    const float* Wk     = (const float*)d_in[2];   // [1024,1024]  (bias unused)

    const size_t NQ = (size_t)B_ * TQ_ * D_;       // 33554432
    const size_t NV = (size_t)B_ * TV_ * D_;
    const size_t NW = (size_t)D_ * U_;             // 1048576

    float* context = (float*)d_out;                          // [16,2048,1024] fp32
    float* align   = (float*)d_out + NQ;                     // [16,2048,2048] fp32

    // context region doubles as P planes (dead before context written)
    short* Phi = (short*)d_out;
    short* Plo = Phi + NQ;
    // align region doubles as Q planes (dead before S written)
    short* Qhi = (short*)align;
    short* Qlo = Qhi + NQ;
    // ws: W planes (4MB) + V planes (128MB) + Vt (64MB) = 196MB
    short* Whi = (short*)d_ws;
    short* Wlo = Whi + NW;
    short* Vhi = Wlo + NW;
    short* Vlo = Vhi + NV;
    short* Vt  = Vlo + NV;

    // 1. splits
    split_f32<<<NQ / 1024, 256, 0, stream>>>(query, Qhi, Qlo);
    split_f32<<<NW / 1024, 256, 0, stream>>>(Wk, Whi, Wlo);
    split_values<<<dim3(D_ / 32, TV_ / 32, B_), dim3(32, 8), 0, stream>>>(
        values, Vhi, Vlo, Vt);

    // 2. P = Q @ W^T  (M=32768, N=1024, K=1024) -> (Phi,Plo) planes
    gemm_nt_planes<1><<<dim3(D_ / 128, (B_ * TQ_) / 128, 1), 256, 0, stream>>>(
        Qhi, Qlo, Whi, Wlo, nullptr, Phi, Plo, U_, U_, D_, U_, 0, 0, 0);

    // 3. S = P @ V^T per batch -> raw scores into align region
    gemm_nt_planes<0><<<dim3(TV_ / 128, TQ_ / 128, B_), 256, 0, stream>>>(
        Phi, Plo, Vhi, Vlo, align, nullptr, nullptr, D_, D_, TV_, D_,
        (size_t)TQ_ * D_, (size_t)TV_ * D_, (size_t)TQ_ * TV_);

    // 4. softmax in place
    softmax_rows<<<B_ * TQ_, 256, 0, stream>>>(align);

    // 5. context = alignment @ V per batch
    gemm_ctx<<<dim3(D_ / 128, TQ_ / 128, B_), 256, 0, stream>>>(
        align, Vt, context, TV_, TV_, D_, TV_,
        (size_t)TQ_ * TV_, (size_t)D_ * TV_, (size_t)TQ_ * D_);
}